// Round 13
// baseline (527.473 us; speedup 1.0000x reference)
//
#include <hip/hip_runtime.h>

#define B_ 16
#define N_ 16384
#define K_ 16

// ---- workspace layout (float offsets) ----
enum : int {
  WS_LAT  = 0,      // 32 x 128 latent (f32, atomicMax-as-uint, relu>=0)
  WS_SEL  = 5632,   // 32 x 48 selected keypoints
  WS_PMIN = 7168,   // 16 x 3
  WS_PMAX = 7216,   // 16 x 3
  WS_CF   = 7264,   // 16 x 512 x 3 cage corners
  WS_W1F  = 31840,  // 64 x 3  bn-folded
  WS_B1F  = 32032,  // 64
  WS_W2T  = 32096,  // 64(c_in) x 128(out) TRANSPOSED, bn-folded (fused path)
  WS_B2F  = 40288,  // 128
  WS_W3F  = 40416,  // 128(c_in) x 128(out), transposed, scale3-folded
  WS_B3F  = 56800,  // 128
  WS_W2F  = 56928,  // 128(out) x 64(c_in) ROW-MAJOR, bn-folded (split path)
  WS_END  = 65120,
  WS_H2G  = 65536   // split path: h2 tensor, 32 x 128 x 16384 f32 = 268 MB
};
#define H2G_FLOATS 67108864ull
#define CLOUD_H2   2097152ull   // 128*16384

enum : int { OUT_DEF=0, OUT_SRCKP=786432, OUT_TGTKP=787200 };

__device__ __forceinline__ float dist2rn(float px,float py,float pz,float sx,float sy,float sz){
  float dx=__fsub_rn(px,sx), dy=__fsub_rn(py,sy), dz=__fsub_rn(pz,sz);
  return __fadd_rn(__fadd_rn(__fmul_rn(dx,dx),__fmul_rn(dy,dy)),__fmul_rn(dz,dz));
}

// ---------------- prep: fold BN into encoder weights ---------------------------
struct EncW {
  const float *w1,*b1,*g1,*be1,*m1,*v1;
  const float *w2,*b2,*g2,*be2,*m2,*v2;
  const float *w3,*b3,*g3,*be3,*m3,*v3;
};

__device__ __forceinline__ float bn_scale(const float* g, const float* v, int ch){
  return g[ch] * (1.0f / sqrtf(v[ch] + 1e-5f));
}

__global__ void prep_kernel(EncW a, float* ws){
  const int stride = gridDim.x*blockDim.x;
  const int tid = blockIdx.x*blockDim.x + threadIdx.x;
  for (int i=tid;i<4096;i+=stride)            // zero latent (atomicMax target)
    ws[WS_LAT+i] = 0.0f;
  for (int i=tid;i<192;i+=stride){            // W1F
    int o=i/3;
    ws[WS_W1F+i] = a.w1[i] * bn_scale(a.g1,a.v1,o);
  }
  for (int i=tid;i<64;i+=stride){             // B1F
    float s = bn_scale(a.g1,a.v1,i);
    ws[WS_B1F+i] = (a.b1[i] - a.m1[i])*s + a.be1[i];
  }
  for (int i=tid;i<8192;i+=stride){           // W2T[c][o] and W2F[o][c]
    int c=i>>7, o=i&127;
    float w = a.w2[o*64+c] * bn_scale(a.g2,a.v2,o);
    ws[WS_W2T+i] = w;
    ws[WS_W2F + o*64 + c] = w;
  }
  for (int i=tid;i<128;i+=stride){
    float s = bn_scale(a.g2,a.v2,i);
    ws[WS_B2F+i] = (a.b2[i] - a.m2[i])*s + a.be2[i];
  }
  for (int i=tid;i<16384;i+=stride){          // W3F[c][j] = w3[j][c]*s3[j]
    int c=i>>7, j=i&127;
    ws[WS_W3F+i] = a.w3[j*128+c] * bn_scale(a.g3,a.v3,j);
  }
  for (int i=tid;i<128;i+=stride){
    float s = bn_scale(a.g3,a.v3,i);
    ws[WS_B3F+i] = (a.b3[i] - a.m3[i])*s + a.be3[i];
  }
}

// ---------------- split path k1: per-point h1+h2 -> global (no LDS/barriers) ---
// Chains: h1 same fmaf form as v8; h2 single acc chain c=0..63 ascending + bias
// + relu == v8's acc2 chain -> bit-identical h2.
__global__ __launch_bounds__(256, 4) void h1h2_kernel(const float* __restrict__ src,
                                                      const float* __restrict__ tgt,
                                                      const float* __restrict__ ws,
                                                      float* __restrict__ h2g){
  const int cloud = blockIdx.y;
  const int gpt = blockIdx.x*256 + threadIdx.x;     // 0..16383
  const float* base = (cloud < B_) ? (src + (size_t)cloud*N_*3)
                                   : (tgt + (size_t)(cloud-B_)*N_*3);
  const float x0=base[gpt*3+0], x1=base[gpt*3+1], x2=base[gpt*3+2];

  const float* w1 = ws + WS_W1F;
  float h1[64];
  #pragma unroll
  for (int o=0;o<64;o++){
    float acc = fmaf(w1[o*3+2],x2, fmaf(w1[o*3+1],x1, w1[o*3]*x0)) + ws[WS_B1F+o];
    h1[o] = fmaxf(acc, 0.0f);
  }

  float* outp = h2g + (size_t)cloud*CLOUD_H2 + gpt;
  const float* w2 = ws + WS_W2F;
  #pragma unroll 2
  for (int o=0;o<128;o++){
    const float* wr = w2 + o*64;
    float acc = 0.0f;
    #pragma unroll
    for (int c=0;c<64;c++) acc = fmaf(h1[c], wr[c], acc);
    outp[(size_t)o*16384] = fmaxf(acc + ws[WS_B2F+o], 0.0f);
  }
}

// ---------------- split path k2: h2 -> latent max (1 barrier) ------------------
// 64-pt tile staged to 32KB LDS; 8 waves own 16 latent channels each.
// Layer-3 chain c=0..127 ascending == v8's accL chain; max is exact.
__global__ __launch_bounds__(512, 8) void latmax_kernel(const float* __restrict__ ws,
                                                        const float* __restrict__ h2g,
                                                        float* __restrict__ lat){
  const int cloud = blockIdx.y;
  const int tile  = blockIdx.x;              // 0..255, 64 pts each
  const int t = threadIdx.x;
  const int lane = t & 63;
  const int wv = __builtin_amdgcn_readfirstlane(t >> 6);   // 0..7

  __shared__ float hs[128*64];   // [c][pt] 32KB
  const float* srcp = h2g + (size_t)cloud*CLOUD_H2 + (size_t)tile*64;
  for (int i=t;i<8192;i+=512){
    int c = i>>6, p = i&63;
    hs[i] = srcp[(size_t)c*16384 + p];
  }
  __syncthreads();

  float acc[16];
  #pragma unroll
  for (int jj=0;jj<16;jj++) acc[jj]=0.0f;
  const float* w3 = ws + WS_W3F + wv*16;
  #pragma unroll 2
  for (int c=0;c<128;c++){
    const float v = hs[c*64 + lane];
    const float* wr = w3 + c*128;
    #pragma unroll
    for (int jj=0;jj<16;jj++)
      acc[jj] = fmaf(wr[jj], v, acc[jj]);
  }

  #pragma unroll
  for (int jj=0;jj<16;jj++){
    float x = fmaxf(acc[jj] + ws[WS_B3F + wv*16 + jj], 0.0f);  // >=0: uint order ok
    #pragma unroll
    for (int off=32; off>0; off>>=1) x = fmaxf(x, __shfl_down(x, off, 64));
    if (lane==0)
      atomicMax((unsigned*)(lat + cloud*128 + wv*16 + jj), __float_as_uint(x));
  }
}

// ---------------- fused encoder v8 (fallback if ws too small) ------------------
__global__ __launch_bounds__(512, 8) void encode_kernel(const float* __restrict__ src,
                                                        const float* __restrict__ tgt,
                                                        const float* __restrict__ ws,
                                                        float* __restrict__ lat){
  const int cloud = blockIdx.y;
  const int tile  = blockIdx.x;              // 128 tiles/cloud, 128 pts each
  const int t = threadIdx.x;
  const int lane = t & 63;
  const int wv = __builtin_amdgcn_readfirstlane(t >> 6);   // 0..7

  const float* base = ((cloud < B_) ? (src + (size_t)cloud*N_*3)
                                    : (tgt + (size_t)(cloud-B_)*N_*3))
                      + (size_t)tile*128*3;

  __shared__ float h1s[64*128];
  __shared__ float h2b[16*128];

  const int p0 = 2*lane;
  {
    const float x0a=base[p0*3+0], x1a=base[p0*3+1], x2a=base[p0*3+2];
    const float x0b=base[p0*3+3], x1b=base[p0*3+4], x2b=base[p0*3+5];
    const float* w1 = ws + WS_W1F;
    #pragma unroll
    for (int k=0;k<8;k++){
      const int o = wv*8 + k;
      const float wx=w1[o*3], wy=w1[o*3+1], wz=w1[o*3+2], bb=ws[WS_B1F+o];
      h1s[o*128+p0]   = fmaxf(fmaf(wz,x2a,fmaf(wy,x1a,wx*x0a))+bb, 0.0f);
      h1s[o*128+p0+1] = fmaxf(fmaf(wz,x2b,fmaf(wy,x1b,wx*x0b))+bb, 0.0f);
    }
  }
  __syncthreads();

  float accL[2][16];
  #pragma unroll
  for (int jj=0;jj<16;jj++){ accL[0][jj]=0.0f; accL[1][jj]=0.0f; }

  #pragma unroll 1
  for (int q=0;q<8;q++){
    float acc2[2][2];
    acc2[0][0]=0.0f; acc2[0][1]=0.0f; acc2[1][0]=0.0f; acc2[1][1]=0.0f;
    const float* w2t = ws + WS_W2T + q*16 + wv*2;
    #pragma unroll 4
    for (int c=0;c<64;c++){
      const float2 a = *(const float2*)&h1s[c*128 + p0];
      #pragma unroll
      for (int oo=0;oo<2;oo++){
        const float w = w2t[c*128 + oo];
        acc2[0][oo] = fmaf(a.x, w, acc2[0][oo]);
        acc2[1][oo] = fmaf(a.y, w, acc2[1][oo]);
      }
    }
    __syncthreads();
    #pragma unroll
    for (int oo=0;oo<2;oo++){
      const float b = ws[WS_B2F + q*16 + wv*2 + oo];
      float2 y;
      y.x = fmaxf(acc2[0][oo]+b, 0.0f);
      y.y = fmaxf(acc2[1][oo]+b, 0.0f);
      *(float2*)&h2b[(wv*2+oo)*128 + p0] = y;
    }
    __syncthreads();

    #pragma unroll 2
    for (int c2=0;c2<16;c2++){
      const float2 a = *(const float2*)&h2b[c2*128 + p0];
      const float* wr = ws + WS_W3F + (q*16+c2)*128 + wv*16;
      #pragma unroll
      for (int jj=0;jj<16;jj++){
        const float w = wr[jj];
        accL[0][jj] = fmaf(a.x, w, accL[0][jj]);
        accL[1][jj] = fmaf(a.y, w, accL[1][jj]);
      }
    }
  }

  #pragma unroll
  for (int jj=0;jj<16;jj++){
    const float b = ws[WS_B3F + wv*16 + jj];
    float x = fmaxf(fmaxf(accL[0][jj]+b, 0.0f), fmaxf(accL[1][jj]+b, 0.0f));
    #pragma unroll
    for (int off=32; off>0; off>>=1) x = fmaxf(x, __shfl_down(x, off, 64));
    if (lane==0)
      atomicMax((unsigned*)(lat + cloud*128 + wv*16 + jj), __float_as_uint(x));
  }
}

// ---------------- FPS + fused kp-MLP + fused src min/max ----------------------
__global__ __launch_bounds__(512) void fps_kernel(const float* __restrict__ src,
                                                  const float* __restrict__ tgt,
                                                  const float* __restrict__ kw1,
                                                  const float* __restrict__ kb1,
                                                  const float* __restrict__ kw2,
                                                  const float* __restrict__ kb2,
                                                  float* ws, float* out){
  const int cloud = blockIdx.x; const int t = threadIdx.x;
  const float* base = (cloud < B_) ? (src + (size_t)cloud*N_*3)
                                   : (tgt + (size_t)(cloud-B_)*N_*3);
  __shared__ float kpl[48];
  __shared__ float h[128];
  __shared__ float rv[512]; __shared__ int ri[512];
  __shared__ float sel[3];

  float px[32], py[32], pz[32];
  #pragma unroll
  for (int k=0;k<32;k++){
    int n = t + k*512;
    px[k]=base[n*3]; py[k]=base[n*3+1]; pz[k]=base[n*3+2];
  }

  const float* lat = ws + WS_LAT + cloud*128;
  if (t < 128){
    float acc = kb1[t];
    const float* w = kw1 + t*128;
    for (int c=0;c<128;c++) acc = fmaf(lat[c], w[c], acc);
    h[t] = fmaxf(acc, 0.0f);
  }
  __syncthreads();
  if (t < 48){
    float acc = kb2[t];
    const float* w = kw2 + t*128;
    for (int c=0;c<128;c++) acc = fmaf(h[c], w[c], acc);
    kpl[t] = acc;
  }
  __syncthreads();

  float mnx=3.4e38f,mny=3.4e38f,mnz=3.4e38f, mxx=-3.4e38f,mxy=-3.4e38f,mxz=-3.4e38f;
  float bv = -1.0f; int bi = 0;
  #pragma unroll 2
  for (int k=0;k<32;k++){
    int n = t + k*512;
    if (cloud < B_){
      mnx=fminf(mnx,px[k]); mny=fminf(mny,py[k]); mnz=fminf(mnz,pz[k]);
      mxx=fmaxf(mxx,px[k]); mxy=fmaxf(mxy,py[k]); mxz=fmaxf(mxz,pz[k]);
    }
    float dmin = 3.4028235e38f;
    #pragma unroll
    for (int j=0;j<K_;j++)
      dmin = fminf(dmin, dist2rn(px[k],py[k],pz[k], kpl[j*3],kpl[j*3+1],kpl[j*3+2]));
    if (dmin > bv){ bv = dmin; bi = n; }
  }

  rv[t]=bv; ri[t]=bi;
  __syncthreads();
  if (t < 64){
    float v = rv[t]; int i = ri[t];
    #pragma unroll
    for (int e=1;e<8;e++){
      float v2=rv[t+64*e]; int i2=ri[t+64*e];
      if (v2 > v || (v2 == v && i2 < i)){ v=v2; i=i2; }
    }
    #pragma unroll
    for (int m=1;m<64;m<<=1){
      float v2=__shfl_xor(v,m,64); int i2=__shfl_xor(i,m,64);
      if (v2 > v || (v2 == v && i2 < i)){ v=v2; i=i2; }
    }
    if (t==0){
      sel[0]=base[i*3]; sel[1]=base[i*3+1]; sel[2]=base[i*3+2];
      float* sw = ws + WS_SEL + cloud*48;
      sw[0]=sel[0]; sw[1]=sel[1]; sw[2]=sel[2];
      size_t o = (cloud<B_) ? (size_t)(OUT_SRCKP + cloud*48) : (size_t)(OUT_TGTKP + (cloud-B_)*48);
      out[o]=sel[0]; out[o+1]=sel[1]; out[o+2]=sel[2];
    }
  }
  __syncthreads();

  if (cloud < B_){
    float vals[6] = {mnx,mny,mnz,mxx,mxy,mxz};
    for (int c=0;c<6;c++){
      rv[t]=vals[c];
      __syncthreads();
      if (t < 64){
        float v = rv[t];
        #pragma unroll
        for (int e=1;e<8;e++){
          float v2 = rv[t+64*e];
          v = (c<3) ? fminf(v,v2) : fmaxf(v,v2);
        }
        #pragma unroll
        for (int m=1;m<64;m<<=1){
          float v2=__shfl_xor(v,m,64);
          v = (c<3) ? fminf(v,v2) : fmaxf(v,v2);
        }
        if (t==0){
          if (c<3) ws[WS_PMIN + cloud*3 + c] = v;
          else     ws[WS_PMAX + cloud*3 + (c-3)] = v;
        }
      }
      __syncthreads();
    }
  }

  float s0=sel[0], s1=sel[1], s2=sel[2];

  float mind[32];
  bv = -1.0f; bi = 0;
  #pragma unroll
  for (int k=0;k<32;k++){
    int n = t + k*512;
    float d = dist2rn(px[k],py[k],pz[k], s0,s1,s2);
    mind[k]=d;
    if (d > bv){ bv=d; bi=n; }
  }

  for (int it=1; it<K_; it++){
    rv[t]=bv; ri[t]=bi;
    __syncthreads();
    if (t < 64){
      float v = rv[t]; int i = ri[t];
      #pragma unroll
      for (int e=1;e<8;e++){
        float v2=rv[t+64*e]; int i2=ri[t+64*e];
        if (v2 > v || (v2 == v && i2 < i)){ v=v2; i=i2; }
      }
      #pragma unroll
      for (int m=1;m<64;m<<=1){
        float v2=__shfl_xor(v,m,64); int i2=__shfl_xor(i,m,64);
        if (v2 > v || (v2 == v && i2 < i)){ v=v2; i=i2; }
      }
      if (t==0){
        sel[0]=base[i*3]; sel[1]=base[i*3+1]; sel[2]=base[i*3+2];
        float* sw = ws + WS_SEL + cloud*48 + it*3;
        sw[0]=sel[0]; sw[1]=sel[1]; sw[2]=sel[2];
        size_t o = (cloud<B_) ? (size_t)(OUT_SRCKP + cloud*48 + it*3)
                              : (size_t)(OUT_TGTKP + (cloud-B_)*48 + it*3);
        out[o]=sel[0]; out[o+1]=sel[1]; out[o+2]=sel[2];
      }
    }
    __syncthreads();
    s0=sel[0]; s1=sel[1]; s2=sel[2];
    if (it < K_-1){
      bv=-1.0f; bi=0;
      #pragma unroll
      for (int k=0;k<32;k++){
        int n = t + k*512;
        float d = dist2rn(px[k],py[k],pz[k], s0,s1,s2);
        float m = fminf(mind[k], d);
        mind[k]=m;
        if (m > bv){ bv=m; bi=n; }
      }
    }
  }
}

// ---------------- cage MLP + corner grid (64 blocks) --------------------------
__global__ void cage_mlp_kernel(const float* __restrict__ ws,
                                const float* __restrict__ cw1, const float* __restrict__ cb1,
                                const float* __restrict__ cw2, const float* __restrict__ cb2,
                                float* __restrict__ wsm){
  const int b = blockIdx.x >> 2, part = blockIdx.x & 3;
  const int t = threadIdx.x;
  __shared__ float diff[48]; __shared__ float h[128];
  if (t<48) diff[t] = __fsub_rn(ws[WS_SEL + (B_+b)*48 + t], ws[WS_SEL + b*48 + t]);
  __syncthreads();
  if (t<128){
    const float* w = cw1 + t*48;
    float acc = cb1[t];
    for (int j=0;j<48;j++) acc = fmaf(diff[j], w[j], acc);
    h[t] = fmaxf(acc, 0.0f);
  }
  __syncthreads();
  for (int o = part*384 + t; o < part*384 + 384; o += 256){
    const float* w = cw2 + o*128;
    float acc = cb2[o];
    for (int c=0;c<128;c++) acc = fmaf(h[c], w[c], acc);
    int flat = o/3, coord = o - flat*3;
    int u = flat>>6, v=(flat>>3)&7, z=flat&7;
    int g = (coord==0)?u:((coord==1)?v:z);
    float gv = (g==7)?1.0f:(float)g*(1.0f/7.0f);
    wsm[WS_CF + b*1536 + o] = gv + acc;
  }
}

// ---------------- trilinear cage deform ---------------------------------------
__global__ __launch_bounds__(256) void deform_kernel(const float* __restrict__ src,
                                                     const float* __restrict__ ws,
                                                     float* __restrict__ out){
  const int b = blockIdx.y;
  const int n = blockIdx.x*256 + threadIdx.x;
  __shared__ float cf[1536];
  for (int i=threadIdx.x;i<1536;i+=256) cf[i] = ws[WS_CF + b*1536 + i];
  __syncthreads();

  const float* p = src + ((size_t)b*N_ + n)*3;
  float pt[3]; int id[3]; float w[3];
  #pragma unroll
  for (int c=0;c<3;c++){
    float pv = p[c];
    float mn = ws[WS_PMIN+b*3+c], mxv = ws[WS_PMAX+b*3+c];
    float denom = __fadd_rn(__fsub_rn(mxv, mn), 1e-6f);
    float tc = __fmul_rn(__fdiv_rn(__fsub_rn(pv, mn), denom), 7.0f);
    int ic = (int)tc; ic = min(max(ic,0),6);
    pt[c]=pv; id[c]=ic; w[c]=__fsub_rn(tc, (float)ic);
  }
  const int flat = (id[0]<<6) + (id[1]<<3) + id[2];
  const float* c000 = cf + flat*3;
  const float wx=w[0], wy=w[1], wz=w[2];
  const float ux=__fsub_rn(1.0f,wx), uy=__fsub_rn(1.0f,wy), uz=__fsub_rn(1.0f,wz);
  const float w000=__fmul_rn(__fmul_rn(ux,uy),uz);
  const float w100=__fmul_rn(__fmul_rn(wx,uy),uz);
  const float w010=__fmul_rn(__fmul_rn(ux,wy),uz);
  const float w110=__fmul_rn(__fmul_rn(wx,wy),uz);
  const float w001=__fmul_rn(__fmul_rn(ux,uy),wz);
  const float w101=__fmul_rn(__fmul_rn(wx,uy),wz);
  const float w011=__fmul_rn(__fmul_rn(ux,wy),wz);
  const float w111=__fmul_rn(__fmul_rn(wx,wy),wz);
  #pragma unroll
  for (int c=0;c<3;c++){
    float d = __fmul_rn(w000, c000[c]);
    d = __fadd_rn(d, __fmul_rn(w100, c000[192+c]));
    d = __fadd_rn(d, __fmul_rn(w010, c000[24+c]));
    d = __fadd_rn(d, __fmul_rn(w110, c000[216+c]));
    d = __fadd_rn(d, __fmul_rn(w001, c000[3+c]));
    d = __fadd_rn(d, __fmul_rn(w101, c000[195+c]));
    d = __fadd_rn(d, __fmul_rn(w011, c000[27+c]));
    d = __fadd_rn(d, __fmul_rn(w111, c000[219+c]));
    out[((size_t)b*N_+n)*3 + c] = __fadd_rn(pt[c], d);
  }
}

// ---------------- launch ------------------------------------------------------
extern "C" void kernel_launch(void* const* d_in, const int* in_sizes, int n_in,
                              void* d_out, int out_size, void* d_ws, size_t ws_size,
                              hipStream_t stream){
  const float* src = (const float*)d_in[0];
  const float* tgt = (const float*)d_in[1];
  float* ws = (float*)d_ws;
  float* out = (float*)d_out;

  EncW ew;
  ew.w1 =(const float*)d_in[2];  ew.b1 =(const float*)d_in[3];
  ew.g1 =(const float*)d_in[4];  ew.be1=(const float*)d_in[5];
  ew.m1 =(const float*)d_in[6];  ew.v1 =(const float*)d_in[7];
  ew.w2 =(const float*)d_in[8];  ew.b2 =(const float*)d_in[9];
  ew.g2 =(const float*)d_in[10]; ew.be2=(const float*)d_in[11];
  ew.m2 =(const float*)d_in[12]; ew.v2 =(const float*)d_in[13];
  ew.w3 =(const float*)d_in[14]; ew.b3 =(const float*)d_in[15];
  ew.g3 =(const float*)d_in[16]; ew.be3=(const float*)d_in[17];
  ew.m3 =(const float*)d_in[18]; ew.v3 =(const float*)d_in[19];

  prep_kernel<<<128, 256, 0, stream>>>(ew, ws);

  // split path needs ws for the 268MB h2 tensor; deterministic branch (graph-safe)
  const size_t need = (size_t)(WS_H2G + H2G_FLOATS) * sizeof(float);
  if (ws_size >= need){
    h1h2_kernel<<<dim3(64,32), 256, 0, stream>>>(src, tgt, ws, ws + WS_H2G);
    latmax_kernel<<<dim3(256,32), 512, 0, stream>>>(ws, ws + WS_H2G, ws + WS_LAT);
  } else {
    encode_kernel<<<dim3(128,32), 512, 0, stream>>>(src, tgt, ws, ws + WS_LAT);
  }

  fps_kernel<<<32, 512, 0, stream>>>(src, tgt,
      (const float*)d_in[20], (const float*)d_in[21],
      (const float*)d_in[22], (const float*)d_in[23], ws, out);
  cage_mlp_kernel<<<64, 256, 0, stream>>>(ws,
      (const float*)d_in[24], (const float*)d_in[25],
      (const float*)d_in[26], (const float*)d_in[27], ws);
  deform_kernel<<<dim3(64,16), 256, 0, stream>>>(src, ws, out);
}

// Round 14
// 525.245 us; speedup vs baseline: 1.0042x; 1.0042x over previous
//
#include <hip/hip_runtime.h>

#define B_ 16
#define N_ 16384
#define K_ 16

// ---- workspace layout (float offsets) ----
enum : int {
  WS_LAT  = 0,      // 32 x 128 latent (f32, atomicMax-as-uint, relu>=0)
  WS_SEL  = 5632,   // 32 x 48 selected keypoints
  WS_PMIN = 7168,   // 16 x 3
  WS_PMAX = 7216,   // 16 x 3
  WS_CF   = 7264,   // 16 x 512 x 3 cage corners
  WS_W1F  = 31840,  // 64 x 3  bn-folded
  WS_B1F  = 32032,  // 64
  WS_W2T  = 32096,  // 64(c_in) x 128(out) TRANSPOSED, bn-folded
  WS_B2F  = 40288,  // 128
  WS_W3F  = 40416,  // 128(c_in) x 128(out), transposed, scale3-folded
  WS_B3F  = 56800,  // 128
  WS_END  = 56928
};

enum : int { OUT_DEF=0, OUT_SRCKP=786432, OUT_TGTKP=787200 };

__device__ __forceinline__ float dist2rn(float px,float py,float pz,float sx,float sy,float sz){
  float dx=__fsub_rn(px,sx), dy=__fsub_rn(py,sy), dz=__fsub_rn(pz,sz);
  return __fadd_rn(__fadd_rn(__fmul_rn(dx,dx),__fmul_rn(dy,dy)),__fmul_rn(dz,dz));
}

// ---------------- prep: fold BN into encoder weights ---------------------------
struct EncW {
  const float *w1,*b1,*g1,*be1,*m1,*v1;
  const float *w2,*b2,*g2,*be2,*m2,*v2;
  const float *w3,*b3,*g3,*be3,*m3,*v3;
};

__device__ __forceinline__ float bn_scale(const float* g, const float* v, int ch){
  return g[ch] * (1.0f / sqrtf(v[ch] + 1e-5f));
}

__global__ void prep_kernel(EncW a, float* ws){
  const int stride = gridDim.x*blockDim.x;
  const int tid = blockIdx.x*blockDim.x + threadIdx.x;
  for (int i=tid;i<4096;i+=stride)            // zero latent (atomicMax target)
    ws[WS_LAT+i] = 0.0f;
  for (int i=tid;i<192;i+=stride){            // W1F
    int o=i/3;
    ws[WS_W1F+i] = a.w1[i] * bn_scale(a.g1,a.v1,o);
  }
  for (int i=tid;i<64;i+=stride){             // B1F
    float s = bn_scale(a.g1,a.v1,i);
    ws[WS_B1F+i] = (a.b1[i] - a.m1[i])*s + a.be1[i];
  }
  for (int i=tid;i<8192;i+=stride){           // W2T[c][o] = w2[o][c]*s2[o]
    int c=i>>7, o=i&127;
    ws[WS_W2T+i] = a.w2[o*64+c] * bn_scale(a.g2,a.v2,o);
  }
  for (int i=tid;i<128;i+=stride){
    float s = bn_scale(a.g2,a.v2,i);
    ws[WS_B2F+i] = (a.b2[i] - a.m2[i])*s + a.be2[i];
  }
  for (int i=tid;i<16384;i+=stride){          // W3F[c][j] = w3[j][c]*s3[j]
    int c=i>>7, j=i&127;
    ws[WS_W3F+i] = a.w3[j*128+c] * bn_scale(a.g3,a.v3,j);
  }
  for (int i=tid;i<128;i+=stride){
    float s = bn_scale(a.g3,a.v3,i);
    ws[WS_B3F+i] = (a.b3[i] - a.m3[i])*s + a.be3[i];
  }
}

// ---------------- encoder v9: LDS overlay, 3 barriers, single-sweep B & C -----
// R12/R13 post-mortem: v8's phase B re-read h1 8x (512 ds_read_b64/lane/tile;
// LDS pipe ~0.83x VALU load) under a 17-barrier lockstep -> busy capped 67%.
// v9: 64KB smem overlay — h1 (32KB) computed once, phase B accumulates ALL 16
// owned h2 channels in ONE c-sweep (64 ds_read_b64), barrier, h2 (64KB,
// overlaying h1) written once, barrier, phase C sweeps 128 channels barrier-
// free. LDS traffic ~3x lower, 3 barriers/tile. 2 blocks/CU (4 waves/SIMD).
// Chains: acc2 over c=0..63 asc, accL over c2=0..127 asc — bit-identical to
// v8 -> same FPS selections.
__global__ __launch_bounds__(512, 4) void encode_kernel(const float* __restrict__ src,
                                                        const float* __restrict__ tgt,
                                                        const float* __restrict__ ws,
                                                        float* __restrict__ lat){
  const int cloud = blockIdx.y;
  const int tile  = blockIdx.x;              // 128 tiles/cloud, 128 pts each
  const int t = threadIdx.x;
  const int lane = t & 63;
  const int wv = __builtin_amdgcn_readfirstlane(t >> 6);   // 0..7

  const float* base = ((cloud < B_) ? (src + (size_t)cloud*N_*3)
                                    : (tgt + (size_t)(cloud-B_)*N_*3))
                      + (size_t)tile*128*3;

  __shared__ float smem[16384];   // 64KB: [0,8192)=h1 then h2 ch0-63; [8192,16384)=h2 ch64-127
  float* h1s = smem;              // [c][pt]  64 x 128
  float* h2s = smem;              // [c2][pt] 128 x 128 (valid after overlay write)

  const int p0 = 2*lane;
  const float x0a=base[p0*3+0], x1a=base[p0*3+1], x2a=base[p0*3+2];
  const float x0b=base[p0*3+3], x1b=base[p0*3+4], x2b=base[p0*3+5];

  // phase A: layer 1 (3->64); wave wv computes channels 8wv..8wv+7
  {
    const float* w1 = ws + WS_W1F;
    #pragma unroll
    for (int k=0;k<8;k++){
      const int o = wv*8 + k;
      const float wx=w1[o*3], wy=w1[o*3+1], wz=w1[o*3+2], bb=ws[WS_B1F+o];
      float2 y;
      y.x = fmaxf(fmaf(wz,x2a,fmaf(wy,x1a,wx*x0a))+bb, 0.0f);
      y.y = fmaxf(fmaf(wz,x2b,fmaf(wy,x1b,wx*x0b))+bb, 0.0f);
      *(float2*)&h1s[o*128+p0] = y;
    }
  }
  __syncthreads();

  // phase B: ALL 16 owned h2 channels (wv*16..+15) in one c-sweep; h1 read once
  float acc2[2][16];
  #pragma unroll
  for (int jj=0;jj<16;jj++){ acc2[0][jj]=0.0f; acc2[1][jj]=0.0f; }
  {
    const float* w2t = ws + WS_W2T + wv*16;   // + c*128 + jj
    #pragma unroll 2
    for (int c=0;c<64;c++){
      const float2 a = *(const float2*)&h1s[c*128 + p0];
      const float* wr = w2t + c*128;
      #pragma unroll
      for (int jj=0;jj<16;jj++){
        const float w = wr[jj];
        acc2[0][jj] = fmaf(a.x, w, acc2[0][jj]);
        acc2[1][jj] = fmaf(a.y, w, acc2[1][jj]);
      }
    }
  }
  __syncthreads();   // all waves done READING h1 before the overlay write

  // h2 bias+relu -> LDS (overlays h1 region for ch<64)
  #pragma unroll
  for (int jj=0;jj<16;jj++){
    const float b = ws[WS_B2F + wv*16 + jj];
    float2 y;
    y.x = fmaxf(acc2[0][jj]+b, 0.0f);
    y.y = fmaxf(acc2[1][jj]+b, 0.0f);
    *(float2*)&h2s[(wv*16+jj)*128 + p0] = y;
  }
  __syncthreads();

  // phase C: layer 3, one barrier-free sweep over all 128 input channels
  float accL[2][16];
  #pragma unroll
  for (int jj=0;jj<16;jj++){ accL[0][jj]=0.0f; accL[1][jj]=0.0f; }
  {
    const float* w3 = ws + WS_W3F + wv*16;    // + c2*128 + jj
    #pragma unroll 2
    for (int c2=0;c2<128;c2++){
      const float2 a = *(const float2*)&h2s[c2*128 + p0];
      const float* wr = w3 + c2*128;
      #pragma unroll
      for (int jj=0;jj<16;jj++){
        const float w = wr[jj];
        accL[0][jj] = fmaf(a.x, w, accL[0][jj]);
        accL[1][jj] = fmaf(a.y, w, accL[1][jj]);
      }
    }
  }

  // bias+relu, max over 2 pts, wave-reduce 64 lanes, one atomic per channel
  #pragma unroll
  for (int jj=0;jj<16;jj++){
    const float b = ws[WS_B3F + wv*16 + jj];
    float x = fmaxf(fmaxf(accL[0][jj]+b, 0.0f), fmaxf(accL[1][jj]+b, 0.0f));
    #pragma unroll
    for (int off=32; off>0; off>>=1) x = fmaxf(x, __shfl_down(x, off, 64));
    if (lane==0)
      atomicMax((unsigned*)(lat + cloud*128 + wv*16 + jj), __float_as_uint(x));
  }
}

// ---------------- FPS + fused kp-MLP + fused src min/max ----------------------
__global__ __launch_bounds__(512) void fps_kernel(const float* __restrict__ src,
                                                  const float* __restrict__ tgt,
                                                  const float* __restrict__ kw1,
                                                  const float* __restrict__ kb1,
                                                  const float* __restrict__ kw2,
                                                  const float* __restrict__ kb2,
                                                  float* ws, float* out){
  const int cloud = blockIdx.x; const int t = threadIdx.x;
  const float* base = (cloud < B_) ? (src + (size_t)cloud*N_*3)
                                   : (tgt + (size_t)(cloud-B_)*N_*3);
  __shared__ float kpl[48];
  __shared__ float h[128];
  __shared__ float rv[512]; __shared__ int ri[512];
  __shared__ float sel[3];

  float px[32], py[32], pz[32];
  #pragma unroll
  for (int k=0;k<32;k++){
    int n = t + k*512;
    px[k]=base[n*3]; py[k]=base[n*3+1]; pz[k]=base[n*3+2];
  }

  const float* lat = ws + WS_LAT + cloud*128;
  if (t < 128){
    float acc = kb1[t];
    const float* w = kw1 + t*128;
    for (int c=0;c<128;c++) acc = fmaf(lat[c], w[c], acc);
    h[t] = fmaxf(acc, 0.0f);
  }
  __syncthreads();
  if (t < 48){
    float acc = kb2[t];
    const float* w = kw2 + t*128;
    for (int c=0;c<128;c++) acc = fmaf(h[c], w[c], acc);
    kpl[t] = acc;
  }
  __syncthreads();

  float mnx=3.4e38f,mny=3.4e38f,mnz=3.4e38f, mxx=-3.4e38f,mxy=-3.4e38f,mxz=-3.4e38f;
  float bv = -1.0f; int bi = 0;
  #pragma unroll 2
  for (int k=0;k<32;k++){
    int n = t + k*512;
    if (cloud < B_){
      mnx=fminf(mnx,px[k]); mny=fminf(mny,py[k]); mnz=fminf(mnz,pz[k]);
      mxx=fmaxf(mxx,px[k]); mxy=fmaxf(mxy,py[k]); mxz=fmaxf(mxz,pz[k]);
    }
    float dmin = 3.4028235e38f;
    #pragma unroll
    for (int j=0;j<K_;j++)
      dmin = fminf(dmin, dist2rn(px[k],py[k],pz[k], kpl[j*3],kpl[j*3+1],kpl[j*3+2]));
    if (dmin > bv){ bv = dmin; bi = n; }
  }

  rv[t]=bv; ri[t]=bi;
  __syncthreads();
  if (t < 64){
    float v = rv[t]; int i = ri[t];
    #pragma unroll
    for (int e=1;e<8;e++){
      float v2=rv[t+64*e]; int i2=ri[t+64*e];
      if (v2 > v || (v2 == v && i2 < i)){ v=v2; i=i2; }
    }
    #pragma unroll
    for (int m=1;m<64;m<<=1){
      float v2=__shfl_xor(v,m,64); int i2=__shfl_xor(i,m,64);
      if (v2 > v || (v2 == v && i2 < i)){ v=v2; i=i2; }
    }
    if (t==0){
      sel[0]=base[i*3]; sel[1]=base[i*3+1]; sel[2]=base[i*3+2];
      float* sw = ws + WS_SEL + cloud*48;
      sw[0]=sel[0]; sw[1]=sel[1]; sw[2]=sel[2];
      size_t o = (cloud<B_) ? (size_t)(OUT_SRCKP + cloud*48) : (size_t)(OUT_TGTKP + (cloud-B_)*48);
      out[o]=sel[0]; out[o+1]=sel[1]; out[o+2]=sel[2];
    }
  }
  __syncthreads();

  if (cloud < B_){
    float vals[6] = {mnx,mny,mnz,mxx,mxy,mxz};
    for (int c=0;c<6;c++){
      rv[t]=vals[c];
      __syncthreads();
      if (t < 64){
        float v = rv[t];
        #pragma unroll
        for (int e=1;e<8;e++){
          float v2 = rv[t+64*e];
          v = (c<3) ? fminf(v,v2) : fmaxf(v,v2);
        }
        #pragma unroll
        for (int m=1;m<64;m<<=1){
          float v2=__shfl_xor(v,m,64);
          v = (c<3) ? fminf(v,v2) : fmaxf(v,v2);
        }
        if (t==0){
          if (c<3) ws[WS_PMIN + cloud*3 + c] = v;
          else     ws[WS_PMAX + cloud*3 + (c-3)] = v;
        }
      }
      __syncthreads();
    }
  }

  float s0=sel[0], s1=sel[1], s2=sel[2];

  float mind[32];
  bv = -1.0f; bi = 0;
  #pragma unroll
  for (int k=0;k<32;k++){
    int n = t + k*512;
    float d = dist2rn(px[k],py[k],pz[k], s0,s1,s2);
    mind[k]=d;
    if (d > bv){ bv=d; bi=n; }
  }

  for (int it=1; it<K_; it++){
    rv[t]=bv; ri[t]=bi;
    __syncthreads();
    if (t < 64){
      float v = rv[t]; int i = ri[t];
      #pragma unroll
      for (int e=1;e<8;e++){
        float v2=rv[t+64*e]; int i2=ri[t+64*e];
        if (v2 > v || (v2 == v && i2 < i)){ v=v2; i=i2; }
      }
      #pragma unroll
      for (int m=1;m<64;m<<=1){
        float v2=__shfl_xor(v,m,64); int i2=__shfl_xor(i,m,64);
        if (v2 > v || (v2 == v && i2 < i)){ v=v2; i=i2; }
      }
      if (t==0){
        sel[0]=base[i*3]; sel[1]=base[i*3+1]; sel[2]=base[i*3+2];
        float* sw = ws + WS_SEL + cloud*48 + it*3;
        sw[0]=sel[0]; sw[1]=sel[1]; sw[2]=sel[2];
        size_t o = (cloud<B_) ? (size_t)(OUT_SRCKP + cloud*48 + it*3)
                              : (size_t)(OUT_TGTKP + (cloud-B_)*48 + it*3);
        out[o]=sel[0]; out[o+1]=sel[1]; out[o+2]=sel[2];
      }
    }
    __syncthreads();
    s0=sel[0]; s1=sel[1]; s2=sel[2];
    if (it < K_-1){
      bv=-1.0f; bi=0;
      #pragma unroll
      for (int k=0;k<32;k++){
        int n = t + k*512;
        float d = dist2rn(px[k],py[k],pz[k], s0,s1,s2);
        float m = fminf(mind[k], d);
        mind[k]=m;
        if (m > bv){ bv=m; bi=n; }
      }
    }
  }
}

// ---------------- cage MLP + corner grid (64 blocks) --------------------------
__global__ void cage_mlp_kernel(const float* __restrict__ ws,
                                const float* __restrict__ cw1, const float* __restrict__ cb1,
                                const float* __restrict__ cw2, const float* __restrict__ cb2,
                                float* __restrict__ wsm){
  const int b = blockIdx.x >> 2, part = blockIdx.x & 3;
  const int t = threadIdx.x;
  __shared__ float diff[48]; __shared__ float h[128];
  if (t<48) diff[t] = __fsub_rn(ws[WS_SEL + (B_+b)*48 + t], ws[WS_SEL + b*48 + t]);
  __syncthreads();
  if (t<128){
    const float* w = cw1 + t*48;
    float acc = cb1[t];
    for (int j=0;j<48;j++) acc = fmaf(diff[j], w[j], acc);
    h[t] = fmaxf(acc, 0.0f);
  }
  __syncthreads();
  for (int o = part*384 + t; o < part*384 + 384; o += 256){
    const float* w = cw2 + o*128;
    float acc = cb2[o];
    for (int c=0;c<128;c++) acc = fmaf(h[c], w[c], acc);
    int flat = o/3, coord = o - flat*3;
    int u = flat>>6, v=(flat>>3)&7, z=flat&7;
    int g = (coord==0)?u:((coord==1)?v:z);
    float gv = (g==7)?1.0f:(float)g*(1.0f/7.0f);
    wsm[WS_CF + b*1536 + o] = gv + acc;
  }
}

// ---------------- trilinear cage deform ---------------------------------------
__global__ __launch_bounds__(256) void deform_kernel(const float* __restrict__ src,
                                                     const float* __restrict__ ws,
                                                     float* __restrict__ out){
  const int b = blockIdx.y;
  const int n = blockIdx.x*256 + threadIdx.x;
  __shared__ float cf[1536];
  for (int i=threadIdx.x;i<1536;i+=256) cf[i] = ws[WS_CF + b*1536 + i];
  __syncthreads();

  const float* p = src + ((size_t)b*N_ + n)*3;
  float pt[3]; int id[3]; float w[3];
  #pragma unroll
  for (int c=0;c<3;c++){
    float pv = p[c];
    float mn = ws[WS_PMIN+b*3+c], mxv = ws[WS_PMAX+b*3+c];
    float denom = __fadd_rn(__fsub_rn(mxv, mn), 1e-6f);
    float tc = __fmul_rn(__fdiv_rn(__fsub_rn(pv, mn), denom), 7.0f);
    int ic = (int)tc; ic = min(max(ic,0),6);
    pt[c]=pv; id[c]=ic; w[c]=__fsub_rn(tc, (float)ic);
  }
  const int flat = (id[0]<<6) + (id[1]<<3) + id[2];
  const float* c000 = cf + flat*3;
  const float wx=w[0], wy=w[1], wz=w[2];
  const float ux=__fsub_rn(1.0f,wx), uy=__fsub_rn(1.0f,wy), uz=__fsub_rn(1.0f,wz);
  const float w000=__fmul_rn(__fmul_rn(ux,uy),uz);
  const float w100=__fmul_rn(__fmul_rn(wx,uy),uz);
  const float w010=__fmul_rn(__fmul_rn(ux,wy),uz);
  const float w110=__fmul_rn(__fmul_rn(wx,wy),uz);
  const float w001=__fmul_rn(__fmul_rn(ux,uy),wz);
  const float w101=__fmul_rn(__fmul_rn(wx,uy),wz);
  const float w011=__fmul_rn(__fmul_rn(ux,wy),wz);
  const float w111=__fmul_rn(__fmul_rn(wx,wy),wz);
  #pragma unroll
  for (int c=0;c<3;c++){
    float d = __fmul_rn(w000, c000[c]);
    d = __fadd_rn(d, __fmul_rn(w100, c000[192+c]));
    d = __fadd_rn(d, __fmul_rn(w010, c000[24+c]));
    d = __fadd_rn(d, __fmul_rn(w110, c000[216+c]));
    d = __fadd_rn(d, __fmul_rn(w001, c000[3+c]));
    d = __fadd_rn(d, __fmul_rn(w101, c000[195+c]));
    d = __fadd_rn(d, __fmul_rn(w011, c000[27+c]));
    d = __fadd_rn(d, __fmul_rn(w111, c000[219+c]));
    out[((size_t)b*N_+n)*3 + c] = __fadd_rn(pt[c], d);
  }
}

// ---------------- launch ------------------------------------------------------
extern "C" void kernel_launch(void* const* d_in, const int* in_sizes, int n_in,
                              void* d_out, int out_size, void* d_ws, size_t ws_size,
                              hipStream_t stream){
  const float* src = (const float*)d_in[0];
  const float* tgt = (const float*)d_in[1];
  float* ws = (float*)d_ws;
  float* out = (float*)d_out;

  EncW ew;
  ew.w1 =(const float*)d_in[2];  ew.b1 =(const float*)d_in[3];
  ew.g1 =(const float*)d_in[4];  ew.be1=(const float*)d_in[5];
  ew.m1 =(const float*)d_in[6];  ew.v1 =(const float*)d_in[7];
  ew.w2 =(const float*)d_in[8];  ew.b2 =(const float*)d_in[9];
  ew.g2 =(const float*)d_in[10]; ew.be2=(const float*)d_in[11];
  ew.m2 =(const float*)d_in[12]; ew.v2 =(const float*)d_in[13];
  ew.w3 =(const float*)d_in[14]; ew.b3 =(const float*)d_in[15];
  ew.g3 =(const float*)d_in[16]; ew.be3=(const float*)d_in[17];
  ew.m3 =(const float*)d_in[18]; ew.v3 =(const float*)d_in[19];

  prep_kernel<<<128, 256, 0, stream>>>(ew, ws);
  encode_kernel<<<dim3(128,32), 512, 0, stream>>>(src, tgt, ws, ws + WS_LAT);
  fps_kernel<<<32, 512, 0, stream>>>(src, tgt,
      (const float*)d_in[20], (const float*)d_in[21],
      (const float*)d_in[22], (const float*)d_in[23], ws, out);
  cage_mlp_kernel<<<64, 256, 0, stream>>>(ws,
      (const float*)d_in[24], (const float*)d_in[25],
      (const float*)d_in[26], (const float*)d_in[27], ws);
  deform_kernel<<<dim3(64,16), 256, 0, stream>>>(src, ws, out);
}

// Round 15
// 515.560 us; speedup vs baseline: 1.0231x; 1.0188x over previous
//
#include <hip/hip_runtime.h>

#define B_ 16
#define N_ 16384
#define K_ 16

// ---- workspace layout (float offsets) ----
enum : int {
  WS_LAT  = 0,      // 32 x 128 latent (f32, atomicMax-as-uint, relu>=0)
  WS_SEL  = 5632,   // 32 x 48 selected keypoints
  WS_PMIN = 7168,   // 16 x 3
  WS_PMAX = 7216,   // 16 x 3
  WS_CF   = 7264,   // 16 x 512 x 3 cage corners
  WS_W1F  = 31840,  // 64 x 3  bn-folded
  WS_B1F  = 32032,  // 64
  WS_W2T  = 32096,  // 64(c_in) x 128(out) TRANSPOSED, bn-folded
  WS_B2F  = 40288,  // 128
  WS_W3F  = 40416,  // 128(c_in) x 128(out), transposed, scale3-folded
  WS_B3F  = 56800,  // 128
  WS_END  = 56928
};

enum : int { OUT_DEF=0, OUT_SRCKP=786432, OUT_TGTKP=787200 };

__device__ __forceinline__ float dist2rn(float px,float py,float pz,float sx,float sy,float sz){
  float dx=__fsub_rn(px,sx), dy=__fsub_rn(py,sy), dz=__fsub_rn(pz,sz);
  return __fadd_rn(__fadd_rn(__fmul_rn(dx,dx),__fmul_rn(dy,dy)),__fmul_rn(dz,dz));
}

// ---------------- prep: fold BN into encoder weights ---------------------------
struct EncW {
  const float *w1,*b1,*g1,*be1,*m1,*v1;
  const float *w2,*b2,*g2,*be2,*m2,*v2;
  const float *w3,*b3,*g3,*be3,*m3,*v3;
};

__device__ __forceinline__ float bn_scale(const float* g, const float* v, int ch){
  return g[ch] * (1.0f / sqrtf(v[ch] + 1e-5f));
}

__global__ void prep_kernel(EncW a, float* ws){
  const int stride = gridDim.x*blockDim.x;
  const int tid = blockIdx.x*blockDim.x + threadIdx.x;
  for (int i=tid;i<4096;i+=stride)            // zero latent (atomicMax target)
    ws[WS_LAT+i] = 0.0f;
  for (int i=tid;i<192;i+=stride){            // W1F
    int o=i/3;
    ws[WS_W1F+i] = a.w1[i] * bn_scale(a.g1,a.v1,o);
  }
  for (int i=tid;i<64;i+=stride){             // B1F
    float s = bn_scale(a.g1,a.v1,i);
    ws[WS_B1F+i] = (a.b1[i] - a.m1[i])*s + a.be1[i];
  }
  for (int i=tid;i<8192;i+=stride){           // W2T[c][o] = w2[o][c]*s2[o]
    int c=i>>7, o=i&127;
    ws[WS_W2T+i] = a.w2[o*64+c] * bn_scale(a.g2,a.v2,o);
  }
  for (int i=tid;i<128;i+=stride){
    float s = bn_scale(a.g2,a.v2,i);
    ws[WS_B2F+i] = (a.b2[i] - a.m2[i])*s + a.be2[i];
  }
  for (int i=tid;i<16384;i+=stride){          // W3F[c][j] = w3[j][c]*s3[j]
    int c=i>>7, j=i&127;
    ws[WS_W3F+i] = a.w3[j*128+c] * bn_scale(a.g3,a.v3,j);
  }
  for (int i=tid;i<128;i+=stride){
    float s = bn_scale(a.g3,a.v3,i);
    ws[WS_B3F+i] = (a.b3[i] - a.m3[i])*s + a.be3[i];
  }
}

// ---------------- encoder v10: v9 structure x 8 waves/SIMD --------------------
// R14 post-mortem: at fixed 4 w/SIMD, v9's barrier/LDS cuts gained only ~2% ->
// occupancy is the stall lever, structure is secondary. v10 = v9's 3-barrier
// overlay with 1024-thread blocks (16 waves, 8 latent ch/wave): 2 blocks/CU x
// 16 waves = 32 waves/CU = 8 w/SIMD at the same 64KB LDS. Per-point FMA/ds/
// s_load totals identical to v9; live regs ~55 < 64-cap at 32 waves/CU.
// Chains: acc2 c=0..63 asc, accL c2=0..127 asc — bit-identical -> same FPS.
__global__ __launch_bounds__(1024, 8) void encode_kernel(const float* __restrict__ src,
                                                         const float* __restrict__ tgt,
                                                         const float* __restrict__ ws,
                                                         float* __restrict__ lat){
  const int cloud = blockIdx.y;
  const int tile  = blockIdx.x;              // 128 tiles/cloud, 128 pts each
  const int t = threadIdx.x;
  const int lane = t & 63;
  const int wv = __builtin_amdgcn_readfirstlane(t >> 6);   // 0..15

  const float* base = ((cloud < B_) ? (src + (size_t)cloud*N_*3)
                                    : (tgt + (size_t)(cloud-B_)*N_*3))
                      + (size_t)tile*128*3;

  __shared__ float smem[16384];   // 64KB overlay: h1 (8192) then h2 (16384)
  float* h1s = smem;              // [c][pt]  64 x 128
  float* h2s = smem;              // [c2][pt] 128 x 128 (valid after overlay write)

  const int p0 = 2*lane;
  const float x0a=base[p0*3+0], x1a=base[p0*3+1], x2a=base[p0*3+2];
  const float x0b=base[p0*3+3], x1b=base[p0*3+4], x2b=base[p0*3+5];

  // phase A: layer 1 (3->64); wave wv computes channels 4wv..4wv+3
  {
    const float* w1 = ws + WS_W1F;
    #pragma unroll
    for (int k=0;k<4;k++){
      const int o = wv*4 + k;
      const float wx=w1[o*3], wy=w1[o*3+1], wz=w1[o*3+2], bb=ws[WS_B1F+o];
      float2 y;
      y.x = fmaxf(fmaf(wz,x2a,fmaf(wy,x1a,wx*x0a))+bb, 0.0f);
      y.y = fmaxf(fmaf(wz,x2b,fmaf(wy,x1b,wx*x0b))+bb, 0.0f);
      *(float2*)&h1s[o*128+p0] = y;
    }
  }
  __syncthreads();

  // phase B: 8 owned h2 channels (wv*8..+7) in one c-sweep; h1 read once
  float acc2[2][8];
  #pragma unroll
  for (int jj=0;jj<8;jj++){ acc2[0][jj]=0.0f; acc2[1][jj]=0.0f; }
  {
    const float* w2t = ws + WS_W2T + wv*8;    // + c*128 + jj (8 contiguous)
    #pragma unroll 2
    for (int c=0;c<64;c++){
      const float2 a = *(const float2*)&h1s[c*128 + p0];
      const float* wr = w2t + c*128;
      #pragma unroll
      for (int jj=0;jj<8;jj++){
        const float w = wr[jj];
        acc2[0][jj] = fmaf(a.x, w, acc2[0][jj]);
        acc2[1][jj] = fmaf(a.y, w, acc2[1][jj]);
      }
    }
  }
  __syncthreads();   // all waves done READING h1 before the overlay write

  // h2 bias+relu -> LDS (overlays h1 region for ch<64)
  #pragma unroll
  for (int jj=0;jj<8;jj++){
    const float b = ws[WS_B2F + wv*8 + jj];
    float2 y;
    y.x = fmaxf(acc2[0][jj]+b, 0.0f);
    y.y = fmaxf(acc2[1][jj]+b, 0.0f);
    *(float2*)&h2s[(wv*8+jj)*128 + p0] = y;
  }
  __syncthreads();

  // phase C: layer 3, one barrier-free sweep over all 128 input channels
  float accL[2][8];
  #pragma unroll
  for (int jj=0;jj<8;jj++){ accL[0][jj]=0.0f; accL[1][jj]=0.0f; }
  {
    const float* w3 = ws + WS_W3F + wv*8;     // + c2*128 + jj (8 contiguous)
    #pragma unroll 2
    for (int c2=0;c2<128;c2++){
      const float2 a = *(const float2*)&h2s[c2*128 + p0];
      const float* wr = w3 + c2*128;
      #pragma unroll
      for (int jj=0;jj<8;jj++){
        const float w = wr[jj];
        accL[0][jj] = fmaf(a.x, w, accL[0][jj]);
        accL[1][jj] = fmaf(a.y, w, accL[1][jj]);
      }
    }
  }

  // bias+relu, max over 2 pts, wave-reduce 64 lanes, one atomic per channel
  #pragma unroll
  for (int jj=0;jj<8;jj++){
    const float b = ws[WS_B3F + wv*8 + jj];
    float x = fmaxf(fmaxf(accL[0][jj]+b, 0.0f), fmaxf(accL[1][jj]+b, 0.0f));
    #pragma unroll
    for (int off=32; off>0; off>>=1) x = fmaxf(x, __shfl_down(x, off, 64));
    if (lane==0)
      atomicMax((unsigned*)(lat + cloud*128 + wv*8 + jj), __float_as_uint(x));
  }
}

// ---------------- FPS + fused kp-MLP + fused src min/max ----------------------
__global__ __launch_bounds__(512) void fps_kernel(const float* __restrict__ src,
                                                  const float* __restrict__ tgt,
                                                  const float* __restrict__ kw1,
                                                  const float* __restrict__ kb1,
                                                  const float* __restrict__ kw2,
                                                  const float* __restrict__ kb2,
                                                  float* ws, float* out){
  const int cloud = blockIdx.x; const int t = threadIdx.x;
  const float* base = (cloud < B_) ? (src + (size_t)cloud*N_*3)
                                   : (tgt + (size_t)(cloud-B_)*N_*3);
  __shared__ float kpl[48];
  __shared__ float h[128];
  __shared__ float rv[512]; __shared__ int ri[512];
  __shared__ float sel[3];

  float px[32], py[32], pz[32];
  #pragma unroll
  for (int k=0;k<32;k++){
    int n = t + k*512;
    px[k]=base[n*3]; py[k]=base[n*3+1]; pz[k]=base[n*3+2];
  }

  const float* lat = ws + WS_LAT + cloud*128;
  if (t < 128){
    float acc = kb1[t];
    const float* w = kw1 + t*128;
    for (int c=0;c<128;c++) acc = fmaf(lat[c], w[c], acc);
    h[t] = fmaxf(acc, 0.0f);
  }
  __syncthreads();
  if (t < 48){
    float acc = kb2[t];
    const float* w = kw2 + t*128;
    for (int c=0;c<128;c++) acc = fmaf(h[c], w[c], acc);
    kpl[t] = acc;
  }
  __syncthreads();

  float mnx=3.4e38f,mny=3.4e38f,mnz=3.4e38f, mxx=-3.4e38f,mxy=-3.4e38f,mxz=-3.4e38f;
  float bv = -1.0f; int bi = 0;
  #pragma unroll 2
  for (int k=0;k<32;k++){
    int n = t + k*512;
    if (cloud < B_){
      mnx=fminf(mnx,px[k]); mny=fminf(mny,py[k]); mnz=fminf(mnz,pz[k]);
      mxx=fmaxf(mxx,px[k]); mxy=fmaxf(mxy,py[k]); mxz=fmaxf(mxz,pz[k]);
    }
    float dmin = 3.4028235e38f;
    #pragma unroll
    for (int j=0;j<K_;j++)
      dmin = fminf(dmin, dist2rn(px[k],py[k],pz[k], kpl[j*3],kpl[j*3+1],kpl[j*3+2]));
    if (dmin > bv){ bv = dmin; bi = n; }
  }

  rv[t]=bv; ri[t]=bi;
  __syncthreads();
  if (t < 64){
    float v = rv[t]; int i = ri[t];
    #pragma unroll
    for (int e=1;e<8;e++){
      float v2=rv[t+64*e]; int i2=ri[t+64*e];
      if (v2 > v || (v2 == v && i2 < i)){ v=v2; i=i2; }
    }
    #pragma unroll
    for (int m=1;m<64;m<<=1){
      float v2=__shfl_xor(v,m,64); int i2=__shfl_xor(i,m,64);
      if (v2 > v || (v2 == v && i2 < i)){ v=v2; i=i2; }
    }
    if (t==0){
      sel[0]=base[i*3]; sel[1]=base[i*3+1]; sel[2]=base[i*3+2];
      float* sw = ws + WS_SEL + cloud*48;
      sw[0]=sel[0]; sw[1]=sel[1]; sw[2]=sel[2];
      size_t o = (cloud<B_) ? (size_t)(OUT_SRCKP + cloud*48) : (size_t)(OUT_TGTKP + (cloud-B_)*48);
      out[o]=sel[0]; out[o+1]=sel[1]; out[o+2]=sel[2];
    }
  }
  __syncthreads();

  if (cloud < B_){
    float vals[6] = {mnx,mny,mnz,mxx,mxy,mxz};
    for (int c=0;c<6;c++){
      rv[t]=vals[c];
      __syncthreads();
      if (t < 64){
        float v = rv[t];
        #pragma unroll
        for (int e=1;e<8;e++){
          float v2 = rv[t+64*e];
          v = (c<3) ? fminf(v,v2) : fmaxf(v,v2);
        }
        #pragma unroll
        for (int m=1;m<64;m<<=1){
          float v2=__shfl_xor(v,m,64);
          v = (c<3) ? fminf(v,v2) : fmaxf(v,v2);
        }
        if (t==0){
          if (c<3) ws[WS_PMIN + cloud*3 + c] = v;
          else     ws[WS_PMAX + cloud*3 + (c-3)] = v;
        }
      }
      __syncthreads();
    }
  }

  float s0=sel[0], s1=sel[1], s2=sel[2];

  float mind[32];
  bv = -1.0f; bi = 0;
  #pragma unroll
  for (int k=0;k<32;k++){
    int n = t + k*512;
    float d = dist2rn(px[k],py[k],pz[k], s0,s1,s2);
    mind[k]=d;
    if (d > bv){ bv=d; bi=n; }
  }

  for (int it=1; it<K_; it++){
    rv[t]=bv; ri[t]=bi;
    __syncthreads();
    if (t < 64){
      float v = rv[t]; int i = ri[t];
      #pragma unroll
      for (int e=1;e<8;e++){
        float v2=rv[t+64*e]; int i2=ri[t+64*e];
        if (v2 > v || (v2 == v && i2 < i)){ v=v2; i=i2; }
      }
      #pragma unroll
      for (int m=1;m<64;m<<=1){
        float v2=__shfl_xor(v,m,64); int i2=__shfl_xor(i,m,64);
        if (v2 > v || (v2 == v && i2 < i)){ v=v2; i=i2; }
      }
      if (t==0){
        sel[0]=base[i*3]; sel[1]=base[i*3+1]; sel[2]=base[i*3+2];
        float* sw = ws + WS_SEL + cloud*48 + it*3;
        sw[0]=sel[0]; sw[1]=sel[1]; sw[2]=sel[2];
        size_t o = (cloud<B_) ? (size_t)(OUT_SRCKP + cloud*48 + it*3)
                              : (size_t)(OUT_TGTKP + (cloud-B_)*48 + it*3);
        out[o]=sel[0]; out[o+1]=sel[1]; out[o+2]=sel[2];
      }
    }
    __syncthreads();
    s0=sel[0]; s1=sel[1]; s2=sel[2];
    if (it < K_-1){
      bv=-1.0f; bi=0;
      #pragma unroll
      for (int k=0;k<32;k++){
        int n = t + k*512;
        float d = dist2rn(px[k],py[k],pz[k], s0,s1,s2);
        float m = fminf(mind[k], d);
        mind[k]=m;
        if (m > bv){ bv=m; bi=n; }
      }
    }
  }
}

// ---------------- cage MLP + corner grid (64 blocks) --------------------------
__global__ void cage_mlp_kernel(const float* __restrict__ ws,
                                const float* __restrict__ cw1, const float* __restrict__ cb1,
                                const float* __restrict__ cw2, const float* __restrict__ cb2,
                                float* __restrict__ wsm){
  const int b = blockIdx.x >> 2, part = blockIdx.x & 3;
  const int t = threadIdx.x;
  __shared__ float diff[48]; __shared__ float h[128];
  if (t<48) diff[t] = __fsub_rn(ws[WS_SEL + (B_+b)*48 + t], ws[WS_SEL + b*48 + t]);
  __syncthreads();
  if (t<128){
    const float* w = cw1 + t*48;
    float acc = cb1[t];
    for (int j=0;j<48;j++) acc = fmaf(diff[j], w[j], acc);
    h[t] = fmaxf(acc, 0.0f);
  }
  __syncthreads();
  for (int o = part*384 + t; o < part*384 + 384; o += 256){
    const float* w = cw2 + o*128;
    float acc = cb2[o];
    for (int c=0;c<128;c++) acc = fmaf(h[c], w[c], acc);
    int flat = o/3, coord = o - flat*3;
    int u = flat>>6, v=(flat>>3)&7, z=flat&7;
    int g = (coord==0)?u:((coord==1)?v:z);
    float gv = (g==7)?1.0f:(float)g*(1.0f/7.0f);
    wsm[WS_CF + b*1536 + o] = gv + acc;
  }
}

// ---------------- trilinear cage deform ---------------------------------------
__global__ __launch_bounds__(256) void deform_kernel(const float* __restrict__ src,
                                                     const float* __restrict__ ws,
                                                     float* __restrict__ out){
  const int b = blockIdx.y;
  const int n = blockIdx.x*256 + threadIdx.x;
  __shared__ float cf[1536];
  for (int i=threadIdx.x;i<1536;i+=256) cf[i] = ws[WS_CF + b*1536 + i];
  __syncthreads();

  const float* p = src + ((size_t)b*N_ + n)*3;
  float pt[3]; int id[3]; float w[3];
  #pragma unroll
  for (int c=0;c<3;c++){
    float pv = p[c];
    float mn = ws[WS_PMIN+b*3+c], mxv = ws[WS_PMAX+b*3+c];
    float denom = __fadd_rn(__fsub_rn(mxv, mn), 1e-6f);
    float tc = __fmul_rn(__fdiv_rn(__fsub_rn(pv, mn), denom), 7.0f);
    int ic = (int)tc; ic = min(max(ic,0),6);
    pt[c]=pv; id[c]=ic; w[c]=__fsub_rn(tc, (float)ic);
  }
  const int flat = (id[0]<<6) + (id[1]<<3) + id[2];
  const float* c000 = cf + flat*3;
  const float wx=w[0], wy=w[1], wz=w[2];
  const float ux=__fsub_rn(1.0f,wx), uy=__fsub_rn(1.0f,wy), uz=__fsub_rn(1.0f,wz);
  const float w000=__fmul_rn(__fmul_rn(ux,uy),uz);
  const float w100=__fmul_rn(__fmul_rn(wx,uy),uz);
  const float w010=__fmul_rn(__fmul_rn(ux,wy),uz);
  const float w110=__fmul_rn(__fmul_rn(wx,wy),uz);
  const float w001=__fmul_rn(__fmul_rn(ux,uy),wz);
  const float w101=__fmul_rn(__fmul_rn(wx,uy),wz);
  const float w011=__fmul_rn(__fmul_rn(ux,wy),wz);
  const float w111=__fmul_rn(__fmul_rn(wx,wy),wz);
  #pragma unroll
  for (int c=0;c<3;c++){
    float d = __fmul_rn(w000, c000[c]);
    d = __fadd_rn(d, __fmul_rn(w100, c000[192+c]));
    d = __fadd_rn(d, __fmul_rn(w010, c000[24+c]));
    d = __fadd_rn(d, __fmul_rn(w110, c000[216+c]));
    d = __fadd_rn(d, __fmul_rn(w001, c000[3+c]));
    d = __fadd_rn(d, __fmul_rn(w101, c000[195+c]));
    d = __fadd_rn(d, __fmul_rn(w011, c000[27+c]));
    d = __fadd_rn(d, __fmul_rn(w111, c000[219+c]));
    out[((size_t)b*N_+n)*3 + c] = __fadd_rn(pt[c], d);
  }
}

// ---------------- launch ------------------------------------------------------
extern "C" void kernel_launch(void* const* d_in, const int* in_sizes, int n_in,
                              void* d_out, int out_size, void* d_ws, size_t ws_size,
                              hipStream_t stream){
  const float* src = (const float*)d_in[0];
  const float* tgt = (const float*)d_in[1];
  float* ws = (float*)d_ws;
  float* out = (float*)d_out;

  EncW ew;
  ew.w1 =(const float*)d_in[2];  ew.b1 =(const float*)d_in[3];
  ew.g1 =(const float*)d_in[4];  ew.be1=(const float*)d_in[5];
  ew.m1 =(const float*)d_in[6];  ew.v1 =(const float*)d_in[7];
  ew.w2 =(const float*)d_in[8];  ew.b2 =(const float*)d_in[9];
  ew.g2 =(const float*)d_in[10]; ew.be2=(const float*)d_in[11];
  ew.m2 =(const float*)d_in[12]; ew.v2 =(const float*)d_in[13];
  ew.w3 =(const float*)d_in[14]; ew.b3 =(const float*)d_in[15];
  ew.g3 =(const float*)d_in[16]; ew.be3=(const float*)d_in[17];
  ew.m3 =(const float*)d_in[18]; ew.v3 =(const float*)d_in[19];

  prep_kernel<<<128, 256, 0, stream>>>(ew, ws);
  encode_kernel<<<dim3(128,32), 1024, 0, stream>>>(src, tgt, ws, ws + WS_LAT);
  fps_kernel<<<32, 512, 0, stream>>>(src, tgt,
      (const float*)d_in[20], (const float*)d_in[21],
      (const float*)d_in[22], (const float*)d_in[23], ws, out);
  cage_mlp_kernel<<<64, 256, 0, stream>>>(ws,
      (const float*)d_in[24], (const float*)d_in[25],
      (const float*)d_in[26], (const float*)d_in[27], ws);
  deform_kernel<<<dim3(64,16), 256, 0, stream>>>(src, ws, out);
}